// Round 8
// baseline (895.321 us; speedup 1.0000x reference)
//
#include <hip/hip_runtime.h>
#include <hip/hip_bf16.h>

// Problem: out[M=4096][N=16384] = x[M][K=4096] @ (W[N][K] * scale[N/128][K/128])^T + bias[N]
#define M_DIM 4096
#define N_DIM 16384
#define K_DIM 4096

typedef __bf16 bf16x8 __attribute__((ext_vector_type(8)));
typedef float f32x4 __attribute__((ext_vector_type(4)));

__device__ __forceinline__ void gload16(const void* g, void* l) {
    __builtin_amdgcn_global_load_lds((__attribute__((address_space(1))) void*)g,
                                     (__attribute__((address_space(3))) void*)l, 16, 0, 0);
}

// ---------- prepass 1: x fp32 -> bf16 ----------
__global__ __launch_bounds__(256) void cvt_x_kernel(const float* __restrict__ x,
                                                    __hip_bfloat16* __restrict__ out,
                                                    int ngroups) {
    int i = blockIdx.x * blockDim.x + threadIdx.x;
    int stride = gridDim.x * blockDim.x;
    for (; i < ngroups; i += stride) {
        const float4* p = (const float4*)(x + (size_t)i * 8);
        float4 v0 = p[0];
        float4 v1 = p[1];
        bf16x8 r;
        r[0] = (__bf16)v0.x; r[1] = (__bf16)v0.y; r[2] = (__bf16)v0.z; r[3] = (__bf16)v0.w;
        r[4] = (__bf16)v1.x; r[5] = (__bf16)v1.y; r[6] = (__bf16)v1.z; r[7] = (__bf16)v1.w;
        *(bf16x8*)(out + (size_t)i * 8) = r;
    }
}

// ---------- prepass 2: W fp32 * blockscale -> bf16 ----------
__global__ __launch_bounds__(256) void dequant_w_kernel(const float* __restrict__ w,
                                                        const float* __restrict__ scale,
                                                        __hip_bfloat16* __restrict__ out) {
    const int ngroups = N_DIM * (K_DIM / 8);
    int i = blockIdx.x * blockDim.x + threadIdx.x;
    int stride = gridDim.x * blockDim.x;
    for (; i < ngroups; i += stride) {
        int row = i >> 9;
        int cg  = i & 511;
        float s = scale[(row >> 7) * (K_DIM / 128) + (cg >> 4)];
        const float4* p = (const float4*)(w + (size_t)i * 8);
        float4 v0 = p[0];
        float4 v1 = p[1];
        bf16x8 r;
        r[0] = (__bf16)(v0.x * s); r[1] = (__bf16)(v0.y * s);
        r[2] = (__bf16)(v0.z * s); r[3] = (__bf16)(v0.w * s);
        r[4] = (__bf16)(v1.x * s); r[5] = (__bf16)(v1.y * s);
        r[6] = (__bf16)(v1.z * s); r[7] = (__bf16)(v1.w * s);
        *(bf16x8*)(out + (size_t)i * 8) = r;
    }
}

// ---------- main GEMM: 256x256, BK=64, 8 waves, counted-lgkm read-ahead -------
// Quadrants/K-tile: P1:Q00(a03,b01) P2:Q01(a03,b23) P3:Q10(a47,b01) P4:Q11(a47,b23).
// Each phase {vmcnt?; stage; ISSUE next frag-group; lgkm(n); BAR; 16 MFMA}.
// Reads issued in phase i complete under phase i's MFMA + barrier, waited in
// phase i+1 with counted lgkm (in-order DS retire):
//   T1 iss b23_t  lgkm(4)  [a03_t,b01_t done]    T2 iss a47_t  lgkm(8)  [b23 done]
//   T3 iss a03_u  lgkm(8)  [a47 done]            T4 iss b01_u  lgkm(12) [free]
//   U1 iss b23_u  lgkm(4)  [a03_u,b01_u done]    ... mirrored; prologue issues
//   a03_t0,b01_t0. Frag lifetimes end exactly at re-issue => single-buffered.
// Stage slots (one bar/phase is sufficient: readers' counted-lgkm precedes
// their phase BAR; stage >= 1 phase later is ordered; per-phase stage/read
// buffers are disjoint, wave skew <= 1 phase):
//   T1: buf1.B1<-u   [buf1.B readers waited <=U2(p-1)]
//   T3: buf0.B0<-t+2 [b23_t waited T2] T4: buf0.A<-t+2 (4) [a47_t waited T3]
//   U1: buf0.B1<-t+2 U3: buf1.B0<-u+2 [b23_u waited U2] U4: buf1.A<-u+2 (4)
// vmcnt(2) at T3/T4/U3/U4 (before stage+issue), each 3-phase slack:
//   T3 keeps T1(2)->buf1.A resident; T4 keeps T3(2)->buf1.B1 resident;
//   U3 keeps U1(2)->buf0.A resident; U4 keeps U3(2)->buf0.B1 resident.
// Steady vm queue entering T1 = 6 = [buf1.B0(2), buf1.A(4)]. Never drains.
__global__ __launch_bounds__(512, 2)
void gemm_bf16_kernel(const __hip_bfloat16* __restrict__ A,   // [M][K] bf16
                      const __hip_bfloat16* __restrict__ Bw,  // [N][K] bf16
                      const float* __restrict__ bias,
                      float* __restrict__ C) {                // [M][N] fp32
    constexpr int Mtiles = M_DIM / 256;            // 16
    constexpr int Ntiles = N_DIM / 256;            // 64
    constexpr int nwg = Mtiles * Ntiles;           // 1024 (div by 8)

    int bid = blockIdx.x;
    int swz = (bid & 7) * (nwg >> 3) + (bid >> 3);   // bijective XCD swizzle
    int bm = swz % Mtiles;
    int bn = swz / Mtiles;

    __shared__ __align__(16) __hip_bfloat16 sA[2][256 * 64];   // 64 KiB
    __shared__ __align__(16) __hip_bfloat16 sB[2][256 * 64];   // 64 KiB

    const int t = threadIdx.x;
    const int l = t & 63;
    const int w = t >> 6;        // wave 0..7
    const int wm = w >> 2;       // 0..1  (M half)
    const int wn = w & 3;        // 0..3  (N quarter)

    const int lr = l & 15;
    const int lk = l >> 4;
    const int rx = (lr & 7) << 3;          // read-side element-col XOR

    // staging (rule #21): linear LDS dest, pre-swizzled global source col.
    const int srow = w * 8 + (l >> 3);
    const int scol = ((l & 7) ^ (l >> 3)) << 3;

    const size_t K = K_DIM;
    const __hip_bfloat16* aB = A  + (size_t)(bm * 256) * K + scol;
    const __hip_bfloat16* bB = Bw + (size_t)(bn * 256) * K + scol;

    f32x4 acc[8][4] = {};

    const int c0 = (lk * 8) ^ rx;
    const int c1 = (32 + lk * 8) ^ rx;
    const int arow = (wm * 128 + lr) * 64;
    const int brow = (wn * 64 + lr) * 64;

    char* A0b = (char*)&sA[0][0] + w * 1024;
    char* B0b = (char*)&sB[0][0] + w * 1024;
    char* A1b = (char*)&sA[1][0] + w * 1024;
    char* B1b = (char*)&sB[1][0] + w * 1024;
    const __hip_bfloat16* pa0 = &sA[0][0];
    const __hip_bfloat16* pb0 = &sB[0][0];
    const __hip_bfloat16* pa1 = &sA[1][0];
    const __hip_bfloat16* pb1 = &sB[1][0];

    bf16x8 a03[4][2], a47[4][2], b01[2][2], b23[2][2];

#define SH(lb, gp)                                                              \
    do {                                                                        \
        gload16((gp) + (size_t)srow * K, (lb));                                 \
        gload16((gp) + (size_t)(64 + srow) * K, (lb) + 8192);                   \
    } while (0)

#define RD_A03(pa_)                                                             \
    { _Pragma("unroll")                                                         \
      for (int mi = 0; mi < 4; ++mi) {                                          \
          a03[mi][0] = *(const bf16x8*)((pa_) + arow + mi * 1024 + c0);         \
          a03[mi][1] = *(const bf16x8*)((pa_) + arow + mi * 1024 + c1);         \
      } }

#define RD_A47(pa_)                                                             \
    { _Pragma("unroll")                                                         \
      for (int mi = 0; mi < 4; ++mi) {                                          \
          a47[mi][0] = *(const bf16x8*)((pa_) + arow + 4096 + mi * 1024 + c0);  \
          a47[mi][1] = *(const bf16x8*)((pa_) + arow + 4096 + mi * 1024 + c1);  \
      } }

#define RD_B01(pb_)                                                             \
    { _Pragma("unroll")                                                         \
      for (int ni = 0; ni < 2; ++ni) {                                          \
          b01[ni][0] = *(const bf16x8*)((pb_) + brow + ni * 1024 + c0);         \
          b01[ni][1] = *(const bf16x8*)((pb_) + brow + ni * 1024 + c1);         \
      } }

#define RD_B23(pb_)                                                             \
    { _Pragma("unroll")                                                         \
      for (int ni = 0; ni < 2; ++ni) {                                          \
          b23[ni][0] = *(const bf16x8*)((pb_) + brow + 2048 + ni * 1024 + c0);  \
          b23[ni][1] = *(const bf16x8*)((pb_) + brow + 2048 + ni * 1024 + c1);  \
      } }

#define MM(mo, no, af, bf)                                                      \
    do {                                                                        \
        __builtin_amdgcn_s_setprio(1);                                          \
        _Pragma("unroll")                                                       \
        for (int s = 0; s < 2; ++s)                                             \
            _Pragma("unroll")                                                   \
            for (int mi = 0; mi < 4; ++mi)                                      \
                _Pragma("unroll")                                               \
                for (int ni = 0; ni < 2; ++ni)                                  \
                    acc[(mo) + mi][(no) + ni] =                                 \
                        __builtin_amdgcn_mfma_f32_16x16x32_bf16(                \
                            af[mi][s], bf[ni][s], acc[(mo) + mi][(no) + ni],    \
                            0, 0, 0);                                           \
        __builtin_amdgcn_s_setprio(0);                                          \
        __builtin_amdgcn_sched_barrier(0);                                      \
    } while (0)

#define SBAR() __builtin_amdgcn_sched_barrier(0)
#define WAITL(n) do { asm volatile("s_waitcnt lgkmcnt(" #n ")" ::: "memory"); SBAR(); } while (0)
#define WAITV(n) do { asm volatile("s_waitcnt vmcnt(" #n ")" ::: "memory"); SBAR(); } while (0)
#define BARS() do { __builtin_amdgcn_s_barrier(); SBAR(); } while (0)

    // ---- prologue: buf0 <- tile0 (8); buf1.B0 <- tile1 (2); buf1.A <- tile1 (4)
    SH(A0b, aB);             SH(A0b + 16384, aB + (size_t)128 * K);
    SH(B0b, bB);             SH(B0b + 16384, bB + (size_t)128 * K);
    SH(B1b, bB + 64);                                            // buf1.B0
    SH(A1b, aB + 64);        SH(A1b + 16384, aB + 64 + (size_t)128 * K);
    WAITV(6);                 // tile0 resident; keep buf1's 6
    BARS();
    RD_A03(pa0);
    RD_B01(pb0);
    SBAR();

    #pragma unroll 1
    for (int p = 0; p < 31; ++p) {
        const __hip_bfloat16* gBu  = bB + (size_t)(2 * p + 1) * 64;
        const __hip_bfloat16* gAt2 = aB + (size_t)(2 * p + 2) * 64;
        const __hip_bfloat16* gBt2 = bB + (size_t)(2 * p + 2) * 64;
        const __hip_bfloat16* gAu2 = aB + (size_t)(2 * p + 3) * 64;
        const __hip_bfloat16* gBu2 = bB + (size_t)(2 * p + 3) * 64;

        // T1: stage buf1.B1(u); issue b23_t; Q00_t
        SH(B1b + 16384, gBu + (size_t)128 * K);
        RD_B23(pb0);
        WAITL(4); BARS();
        MM(0, 0, a03, b01);

        // T2: issue a47_t; Q01_t
        RD_A47(pa0);
        WAITL(8); BARS();
        MM(0, 2, a03, b23);

        // T3: vmcnt keeps T1(2); stage buf0.B0(t+2); issue a03_u; Q10_t
        WAITV(2);
        SH(B0b, gBt2);
        RD_A03(pa1);
        WAITL(8); BARS();
        MM(4, 0, a47, b01);

        // T4: vmcnt keeps T3(2); stage buf0.A(t+2); issue b01_u; Q11_t
        WAITV(2);
        SH(A0b, gAt2);       SH(A0b + 16384, gAt2 + (size_t)128 * K);
        RD_B01(pb1);
        WAITL(12); BARS();
        MM(4, 2, a47, b23);

        // U1: stage buf0.B1(t+2); issue b23_u; Q00_u
        SH(B0b + 16384, gBt2 + (size_t)128 * K);
        RD_B23(pb1);
        WAITL(4); BARS();
        MM(0, 0, a03, b01);

        // U2: issue a47_u; Q01_u
        RD_A47(pa1);
        WAITL(8); BARS();
        MM(0, 2, a03, b23);

        // U3: vmcnt keeps U1(2); stage buf1.B0(u+2); issue a03_{t+2}; Q10_u
        WAITV(2);
        SH(B1b, gBu2);
        RD_A03(pa0);
        WAITL(8); BARS();
        MM(4, 0, a47, b01);

        // U4: vmcnt keeps U3(2); stage buf1.A(u+2); issue b01_{t+2}; Q11_u
        WAITV(2);
        SH(A1b, gAu2);       SH(A1b + 16384, gAu2 + (size_t)128 * K);
        RD_B01(pb0);
        WAITL(12); BARS();
        MM(4, 2, a47, b23);
    }

    // ---- tail p=31: t=62 (buf0), u=63 (buf1); no further stages/prefetch ----
    {
        const __hip_bfloat16* gBu = bB + (size_t)63 * 64;
        // T1: stage buf1.B1(63); issue b23_t; Q00_t
        SH(B1b + 16384, gBu + (size_t)128 * K);
        RD_B23(pb0);
        WAITL(4); BARS();
        MM(0, 0, a03, b01);
        // T2
        RD_A47(pa0);
        WAITL(8); BARS();
        MM(0, 2, a03, b23);
        // T3: vmcnt(2) retires buf1.B0+A stages, keeps T1's B1
        WAITV(2);
        RD_A03(pa1);
        WAITL(8); BARS();
        MM(4, 0, a47, b01);
        // T4: drain T1's stage before b01_u
        WAITV(0);
        RD_B01(pb1);
        WAITL(12); BARS();
        MM(4, 2, a47, b23);
        // U1
        RD_B23(pb1);
        WAITL(4); BARS();
        MM(0, 0, a03, b01);
        // U2
        RD_A47(pa1);
        WAITL(8); BARS();
        MM(0, 2, a03, b23);
        // U3
        WAITL(0); BARS();
        MM(4, 0, a47, b01);
        // U4
        WAITL(0); BARS();
        MM(4, 2, a47, b23);
    }
#undef SH
#undef RD_A03
#undef RD_A47
#undef RD_B01
#undef RD_B23
#undef MM
#undef SBAR
#undef WAITL
#undef WAITV
#undef BARS

    // epilogue: C/D layout col=lane&15, row=(lane>>4)*4+reg  [m89-verified]
    const int crow0 = bm * 256 + wm * 128;
    const int ccol0 = bn * 256 + wn * 64;
    #pragma unroll
    for (int ni = 0; ni < 4; ++ni) {
        int col = ccol0 + ni * 16 + lr;
        float bv = bias[col];
        #pragma unroll
        for (int mi = 0; mi < 8; ++mi) {
            int rbase = crow0 + mi * 16 + lk * 4;
            #pragma unroll
            for (int j = 0; j < 4; ++j) {
                C[(size_t)(rbase + j) * N_DIM + col] = acc[mi][ni][j] + bv;
            }
        }
    }
}

// ---------- fallback (ws too small): fp32 LDS-tiled, correct but slow ----------
__global__ __launch_bounds__(256)
void gemm_fallback(const float* __restrict__ X, const float* __restrict__ W,
                   const float* __restrict__ scale, const float* __restrict__ bias,
                   float* __restrict__ C) {
    int bm = blockIdx.x % (M_DIM / 64);
    int bn = blockIdx.x / (M_DIM / 64);
    __shared__ float sA[64][33];
    __shared__ float sB[64][33];
    int t = threadIdx.x;
    int tx = t & 15, ty = t >> 4;
    float acc[4][4] = {};
    for (int kt = 0; kt < K_DIM / 32; ++kt) {
        float s = scale[(bn >> 1) * (K_DIM / 128) + (kt >> 2)];
        #pragma unroll
        for (int i = 0; i < 8; ++i) {
            int idx = t + i * 256;
            int r = idx >> 5, c = idx & 31;
            sA[r][c] = X[(size_t)(bm * 64 + r) * K_DIM + kt * 32 + c];
            sB[r][c] = W[(size_t)(bn * 64 + r) * K_DIM + kt * 32 + c] * s;
        }
        __syncthreads();
        #pragma unroll
        for (int k = 0; k < 32; ++k) {
            float a[4], b[4];
            #pragma unroll
            for (int i = 0; i < 4; ++i) a[i] = sA[ty * 4 + i][k];
            #pragma unroll
            for (int j = 0; j < 4; ++j) b[j] = sB[tx * 4 + j][k];
            #pragma unroll
            for (int i = 0; i < 4; ++i)
                #pragma unroll
                for (int j = 0; j < 4; ++j) acc[i][j] += a[i] * b[j];
        }
        __syncthreads();
    }
    #pragma unroll
    for (int i = 0; i < 4; ++i)
        #pragma unroll
        for (int j = 0; j < 4; ++j) {
            int row = bm * 64 + ty * 4 + i;
            int col = bn * 64 + tx * 4 + j;
            C[(size_t)row * N_DIM + col] = acc[i][j] + bias[col];
        }
}

extern "C" void kernel_launch(void* const* d_in, const int* in_sizes, int n_in,
                              void* d_out, int out_size, void* d_ws, size_t ws_size,
                              hipStream_t stream) {
    const float* x     = (const float*)d_in[0];   // [2,2048,4096]
    const float* wgt   = (const float*)d_in[1];   // [16384,4096]
    const float* scale = (const float*)d_in[2];   // [128,32]
    const float* bias  = (const float*)d_in[3];   // [16384]
    float* out = (float*)d_out;                   // [2,2048,16384]

    const size_t need = ((size_t)M_DIM * K_DIM + (size_t)N_DIM * K_DIM) * sizeof(__hip_bfloat16);
    if (ws_size >= need) {
        __hip_bfloat16* xbf = (__hip_bfloat16*)d_ws;
        __hip_bfloat16* wbf = xbf + (size_t)M_DIM * K_DIM;
        cvt_x_kernel<<<2048, 256, 0, stream>>>(x, xbf, M_DIM * K_DIM / 8);
        dequant_w_kernel<<<4096, 256, 0, stream>>>(wgt, scale, wbf);
        gemm_bf16_kernel<<<(M_DIM / 256) * (N_DIM / 256), 512, 0, stream>>>(xbf, wbf, bias, out);
    } else {
        gemm_fallback<<<(M_DIM / 64) * (N_DIM / 64), 256, 0, stream>>>(x, wgt, scale, bias, out);
    }
}

// Round 9
// 712.345 us; speedup vs baseline: 1.2569x; 1.2569x over previous
//
#include <hip/hip_runtime.h>
#include <hip/hip_bf16.h>

// Problem: out[M=4096][N=16384] = x[M][K=4096] @ (W[N][K] * scale[N/128][K/128])^T + bias[N]
#define M_DIM 4096
#define N_DIM 16384
#define K_DIM 4096

typedef __bf16 bf16x8 __attribute__((ext_vector_type(8)));
typedef float f32x4 __attribute__((ext_vector_type(4)));

__device__ __forceinline__ void gload16(const void* g, void* l) {
    __builtin_amdgcn_global_load_lds((__attribute__((address_space(1))) void*)g,
                                     (__attribute__((address_space(3))) void*)l, 16, 0, 0);
}

// ---------- prepass 1: x fp32 -> bf16 ----------
__global__ __launch_bounds__(256) void cvt_x_kernel(const float* __restrict__ x,
                                                    __hip_bfloat16* __restrict__ out,
                                                    int ngroups) {
    int i = blockIdx.x * blockDim.x + threadIdx.x;
    int stride = gridDim.x * blockDim.x;
    for (; i < ngroups; i += stride) {
        const float4* p = (const float4*)(x + (size_t)i * 8);
        float4 v0 = p[0];
        float4 v1 = p[1];
        bf16x8 r;
        r[0] = (__bf16)v0.x; r[1] = (__bf16)v0.y; r[2] = (__bf16)v0.z; r[3] = (__bf16)v0.w;
        r[4] = (__bf16)v1.x; r[5] = (__bf16)v1.y; r[6] = (__bf16)v1.z; r[7] = (__bf16)v1.w;
        *(bf16x8*)(out + (size_t)i * 8) = r;
    }
}

// ---------- prepass 2: W fp32 * blockscale -> bf16 ----------
__global__ __launch_bounds__(256) void dequant_w_kernel(const float* __restrict__ w,
                                                        const float* __restrict__ scale,
                                                        __hip_bfloat16* __restrict__ out) {
    const int ngroups = N_DIM * (K_DIM / 8);
    int i = blockIdx.x * blockDim.x + threadIdx.x;
    int stride = gridDim.x * blockDim.x;
    for (; i < ngroups; i += stride) {
        int row = i >> 9;
        int cg  = i & 511;
        float s = scale[(row >> 7) * (K_DIM / 128) + (cg >> 4)];
        const float4* p = (const float4*)(w + (size_t)i * 8);
        float4 v0 = p[0];
        float4 v1 = p[1];
        bf16x8 r;
        r[0] = (__bf16)(v0.x * s); r[1] = (__bf16)(v0.y * s);
        r[2] = (__bf16)(v0.z * s); r[3] = (__bf16)(v0.w * s);
        r[4] = (__bf16)(v1.x * s); r[5] = (__bf16)(v1.y * s);
        r[6] = (__bf16)(v1.z * s); r[7] = (__bf16)(v1.w * s);
        *(bf16x8*)(out + (size_t)i * 8) = r;
    }
}

// ---------- main GEMM: 256x256, BK=64, 8 waves, 8-phase, minimal fences ------
// Structure identical to round-7 (m201 8-phase port: per phase {ds_reads;
// stage 1 half-tile; [lgkm8 if 12 reads]; BAR; lgkm0; setprio 16-MFMA; BAR},
// vmcnt(4) at P4/P8 only). CHANGE vs r7: all sched_barrier(0) removed EXCEPT
// the rule-#18 fence right after each lgkmcnt(0) that gates a register-MFMA
// cluster (and one after P4/P8's BAR to keep stage-issue ahead of the
// read-free MFMA). Memory<->memory order is preserved by asm "memory"
// clobbers + barriers; register dataflow is SSA-tracked, so the compiler is
// now free to interleave next-phase ds_read issue under MFMA drain (the m97
// fine-grained lgkmcnt(4/3/1/0) interleave m141 showed pinning destroys).
// vmcnt(4)@P4 safety (per-thread queue, 2 gloads/phase): outstanding at P4 =
// [P7',P8' (4 left by P8' vmcnt4)] + P1..P4 (8) = 12; retire 8 oldest =
// P7',P8',P1,P2 => buf1 (A from P1/P2, B from P7'/P8') fully resident for
// P5-P8. Mirrored at P8. Last iter peeled to vmcnt(0).
__global__ __launch_bounds__(512, 2)
void gemm_bf16_kernel(const __hip_bfloat16* __restrict__ A,   // [M][K] bf16
                      const __hip_bfloat16* __restrict__ Bw,  // [N][K] bf16
                      const float* __restrict__ bias,
                      float* __restrict__ C) {                // [M][N] fp32
    constexpr int Mtiles = M_DIM / 256;            // 16
    constexpr int Ntiles = N_DIM / 256;            // 64
    constexpr int nwg = Mtiles * Ntiles;           // 1024 (div by 8)

    int bid = blockIdx.x;
    int swz = (bid & 7) * (nwg >> 3) + (bid >> 3);   // bijective XCD swizzle
    int bm = swz % Mtiles;
    int bn = swz / Mtiles;

    __shared__ __align__(16) __hip_bfloat16 sA[2][256 * 64];   // 64 KiB
    __shared__ __align__(16) __hip_bfloat16 sB[2][256 * 64];   // 64 KiB

    const int t = threadIdx.x;
    const int l = t & 63;
    const int w = t >> 6;        // wave 0..7
    const int wm = w >> 2;       // 0..1  (M half)
    const int wn = w & 3;        // 0..3  (N quarter)

    const int lr = l & 15;
    const int lk = l >> 4;
    const int rx = (lr & 7) << 3;          // read-side element-col XOR

    // staging (rule #21): linear LDS dest, pre-swizzled global source col.
    const int srow = w * 8 + (l >> 3);
    const int scol = ((l & 7) ^ (l >> 3)) << 3;

    const size_t K = K_DIM;
    const __hip_bfloat16* aB = A  + (size_t)(bm * 256) * K + scol;
    const __hip_bfloat16* bB = Bw + (size_t)(bn * 256) * K + scol;

    f32x4 acc[8][4] = {};

    const int c0 = (lk * 8) ^ rx;
    const int c1 = (32 + lk * 8) ^ rx;
    const int arow = (wm * 128 + lr) * 64;
    const int brow = (wn * 64 + lr) * 64;

    char* A0b = (char*)&sA[0][0] + w * 1024;   // + half*16384 (+l*16 by hw)
    char* B0b = (char*)&sB[0][0] + w * 1024;
    char* A1b = (char*)&sA[1][0] + w * 1024;
    char* B1b = (char*)&sB[1][0] + w * 1024;

// stage one half-tile (128 rows x 64 cols): 2 gloads/thread
#define SH(lbase, gptr)                                                         \
    do {                                                                        \
        gload16((gptr) + (size_t)srow * K, (lbase));                            \
        gload16((gptr) + (size_t)(64 + srow) * K, (lbase) + 8192);              \
    } while (0)

#define RD_A(dst, off)                                                          \
    _Pragma("unroll")                                                           \
    for (int mi = 0; mi < 4; ++mi) {                                            \
        dst[mi][0] = *(const bf16x8*)(pa_ + arow + (off) + mi * 1024 + c0);     \
        dst[mi][1] = *(const bf16x8*)(pa_ + arow + (off) + mi * 1024 + c1);     \
    }

#define RD_B(dst, off)                                                          \
    _Pragma("unroll")                                                           \
    for (int ni = 0; ni < 2; ++ni) {                                            \
        dst[ni][0] = *(const bf16x8*)(pb_ + brow + (off) + ni * 1024 + c0);     \
        dst[ni][1] = *(const bf16x8*)(pb_ + brow + (off) + ni * 1024 + c1);     \
    }

#define MM(mo, no, af, bf)                                                      \
    do {                                                                        \
        __builtin_amdgcn_s_setprio(1);                                          \
        _Pragma("unroll")                                                       \
        for (int s = 0; s < 2; ++s)                                             \
            _Pragma("unroll")                                                   \
            for (int mi = 0; mi < 4; ++mi)                                      \
                _Pragma("unroll")                                               \
                for (int ni = 0; ni < 2; ++ni)                                  \
                    acc[(mo) + mi][(no) + ni] =                                 \
                        __builtin_amdgcn_mfma_f32_16x16x32_bf16(                \
                            af[mi][s], bf[ni][s], acc[(mo) + mi][(no) + ni],    \
                            0, 0, 0);                                           \
        __builtin_amdgcn_s_setprio(0);                                          \
    } while (0)

#define BAR()   __builtin_amdgcn_s_barrier()
#define SBAR()  __builtin_amdgcn_sched_barrier(0)
#define LGKM0() do { asm volatile("s_waitcnt lgkmcnt(0)" ::: "memory"); SBAR(); } while (0)

    bf16x8 a03[4][2], a47[4][2], b01[2][2], b23[2][2];

    // prologue: tile0 full -> buf0; tile1 B halves -> buf1.B ; keep newest 4
    SH(A0b, aB);  SH(A0b + 16384, aB + (size_t)128 * K);
    SH(B0b, bB);  SH(B0b + 16384, bB + (size_t)128 * K);
    SH(B1b, bB + 64);  SH(B1b + 16384, bB + 64 + (size_t)128 * K);
    asm volatile("s_waitcnt vmcnt(4)" ::: "memory");   // tile0 resident
    BAR();

    #pragma unroll 1
    for (int p = 0; p < 32; ++p) {
        const bool last = (p == 31);
        const __hip_bfloat16* gAu  = aB + (size_t)(2 * p + 1) * 64;
        const __hip_bfloat16* gAt2 = aB + (size_t)(2 * p + 2) * 64;
        const __hip_bfloat16* gBt2 = bB + (size_t)(2 * p + 2) * 64;
        const __hip_bfloat16* gBt3 = bB + (size_t)(2 * p + 3) * 64;
        const __hip_bfloat16* pa_;
        const __hip_bfloat16* pb_;

        // ================= K-tile t = 2p (buf0) =================
        pa_ = &sA[0][0]; pb_ = &sB[0][0];
        // --- P1: reads a03,b01 (12); stage buf1.A0<-u ---
        RD_A(a03, 0); RD_B(b01, 0);
        SH(A1b, gAu);
        asm volatile("s_waitcnt lgkmcnt(8)" ::: "memory");
        BAR();
        LGKM0();
        MM(0, 0, a03, b01);
        BAR();
        // --- P2: reads b23 (4); stage buf1.A1<-u ---
        RD_B(b23, 2048);
        SH(A1b + 16384, gAu + (size_t)128 * K);
        BAR();
        LGKM0();
        MM(0, 2, a03, b23);
        BAR();
        // --- P3: reads a47 (8); stage buf0.B0<-t2 ---
        RD_A(a47, 4096);
        if (!last) SH(B0b, gBt2);
        BAR();
        LGKM0();
        MM(4, 0, a47, b01);
        BAR();
        // --- P4: stage buf0.B1<-t2; vmcnt(4) -> buf1 resident ---
        if (!last) {
            SH(B0b + 16384, gBt2 + (size_t)128 * K);
            asm volatile("s_waitcnt vmcnt(4)" ::: "memory");
        } else {
            asm volatile("s_waitcnt vmcnt(0)" ::: "memory");
        }
        BAR();
        SBAR();
        MM(4, 2, a47, b23);
        BAR();

        // ================= K-tile u = 2p+1 (buf1) =================
        pa_ = &sA[1][0]; pb_ = &sB[1][0];
        // --- P5: reads a03,b01 (12); stage buf0.A0<-t2 ---
        RD_A(a03, 0); RD_B(b01, 0);
        if (!last) SH(A0b, gAt2);
        asm volatile("s_waitcnt lgkmcnt(8)" ::: "memory");
        BAR();
        LGKM0();
        MM(0, 0, a03, b01);
        BAR();
        // --- P6: reads b23 (4); stage buf0.A1<-t2 ---
        RD_B(b23, 2048);
        if (!last) SH(A0b + 16384, gAt2 + (size_t)128 * K);
        BAR();
        LGKM0();
        MM(0, 2, a03, b23);
        BAR();
        // --- P7: reads a47 (8); stage buf1.B0<-t3 ---
        RD_A(a47, 4096);
        if (!last) SH(B1b, gBt3);
        BAR();
        LGKM0();
        MM(4, 0, a47, b01);
        BAR();
        // --- P8: stage buf1.B1<-t3; vmcnt(4) -> buf0 (t2) resident ---
        if (!last) {
            SH(B1b + 16384, gBt3 + (size_t)128 * K);
            asm volatile("s_waitcnt vmcnt(4)" ::: "memory");
        }
        BAR();
        SBAR();
        MM(4, 2, a47, b23);
        if (!last) BAR();
    }
#undef SH
#undef RD_A
#undef RD_B
#undef MM
#undef BAR
#undef SBAR
#undef LGKM0

    // epilogue: C/D layout col=lane&15, row=(lane>>4)*4+reg  [m89-verified]
    const int crow0 = bm * 256 + wm * 128;
    const int ccol0 = bn * 256 + wn * 64;
    #pragma unroll
    for (int ni = 0; ni < 4; ++ni) {
        int col = ccol0 + ni * 16 + lr;
        float bv = bias[col];
        #pragma unroll
        for (int mi = 0; mi < 8; ++mi) {
            int rbase = crow0 + mi * 16 + lk * 4;
            #pragma unroll
            for (int j = 0; j < 4; ++j) {
                C[(size_t)(rbase + j) * N_DIM + col] = acc[mi][ni][j] + bv;
            }
        }
    }
}

// ---------- fallback (ws too small): fp32 LDS-tiled, correct but slow ----------
__global__ __launch_bounds__(256)
void gemm_fallback(const float* __restrict__ X, const float* __restrict__ W,
                   const float* __restrict__ scale, const float* __restrict__ bias,
                   float* __restrict__ C) {
    int bm = blockIdx.x % (M_DIM / 64);
    int bn = blockIdx.x / (M_DIM / 64);
    __shared__ float sA[64][33];
    __shared__ float sB[64][33];
    int t = threadIdx.x;
    int tx = t & 15, ty = t >> 4;
    float acc[4][4] = {};
    for (int kt = 0; kt < K_DIM / 32; ++kt) {
        float s = scale[(bn >> 1) * (K_DIM / 128) + (kt >> 2)];
        #pragma unroll
        for (int i = 0; i < 8; ++i) {
            int idx = t + i * 256;
            int r = idx >> 5, c = idx & 31;
            sA[r][c] = X[(size_t)(bm * 64 + r) * K_DIM + kt * 32 + c];
            sB[r][c] = W[(size_t)(bn * 64 + r) * K_DIM + kt * 32 + c] * s;
        }
        __syncthreads();
        #pragma unroll
        for (int k = 0; k < 32; ++k) {
            float a[4], b[4];
            #pragma unroll
            for (int i = 0; i < 4; ++i) a[i] = sA[ty * 4 + i][k];
            #pragma unroll
            for (int j = 0; j < 4; ++j) b[j] = sB[tx * 4 + j][k];
            #pragma unroll
            for (int i = 0; i < 4; ++i)
                #pragma unroll
                for (int j = 0; j < 4; ++j) acc[i][j] += a[i] * b[j];
        }
        __syncthreads();
    }
    #pragma unroll
    for (int i = 0; i < 4; ++i)
        #pragma unroll
        for (int j = 0; j < 4; ++j) {
            int row = bm * 64 + ty * 4 + i;
            int col = bn * 64 + tx * 4 + j;
            C[(size_t)row * N_DIM + col] = acc[i][j] + bias[col];
        }
}

extern "C" void kernel_launch(void* const* d_in, const int* in_sizes, int n_in,
                              void* d_out, int out_size, void* d_ws, size_t ws_size,
                              hipStream_t stream) {
    const float* x     = (const float*)d_in[0];   // [2,2048,4096]
    const float* wgt   = (const float*)d_in[1];   // [16384,4096]
    const float* scale = (const float*)d_in[2];   // [128,32]
    const float* bias  = (const float*)d_in[3];   // [16384]
    float* out = (float*)d_out;                   // [2,2048,16384]

    const size_t need = ((size_t)M_DIM * K_DIM + (size_t)N_DIM * K_DIM) * sizeof(__hip_bfloat16);
    if (ws_size >= need) {
        __hip_bfloat16* xbf = (__hip_bfloat16*)d_ws;
        __hip_bfloat16* wbf = xbf + (size_t)M_DIM * K_DIM;
        cvt_x_kernel<<<2048, 256, 0, stream>>>(x, xbf, M_DIM * K_DIM / 8);
        dequant_w_kernel<<<4096, 256, 0, stream>>>(wgt, scale, wbf);
        gemm_bf16_kernel<<<(M_DIM / 256) * (N_DIM / 256), 512, 0, stream>>>(xbf, wbf, bias, out);
    } else {
        gemm_fallback<<<(M_DIM / 64) * (N_DIM / 64), 256, 0, stream>>>(x, wgt, scale, bias, out);
    }
}